// Round 3
// baseline (304.593 us; speedup 1.0000x reference)
//
#include <hip/hip_runtime.h>
#include <hip/hip_bf16.h>

// C[m][o] = sum_i x[m][i] * ternary[o][i] * scales[o*32 + i/128]
// M=8192, N=4096, K=4096. Prepass to bf16 (x cvt, W dequant) in d_ws,
// then 256x256 8-phase bf16 NT-GEMM (T2 swizzle + T3/T4 counted vmcnt + T5 setprio
// + T1 chunked XCD swizzle + deepened stage->wait distance).

#define Msz 8192
#define Nsz 4096
#define Ksz 4096

typedef __attribute__((ext_vector_type(8))) short short8;
typedef __attribute__((ext_vector_type(4))) float f32x4;
typedef __attribute__((ext_vector_type(4))) int int4v;
typedef __attribute__((ext_vector_type(4))) float float4v;
typedef __attribute__((ext_vector_type(8))) unsigned short ushort8;

static __device__ __forceinline__ unsigned short f2bf(float f) {
    unsigned u = __builtin_bit_cast(unsigned, f);
    u += 0x7fffu + ((u >> 16) & 1u);
    return (unsigned short)(u >> 16);
}

// ---------------- prepass 1: x fp32 -> bf16 ----------------
__global__ void cvt_x(const float* __restrict__ x, unsigned short* __restrict__ o, int n8) {
    int i = blockIdx.x * blockDim.x + threadIdx.x;
    int stride = gridDim.x * blockDim.x;
    for (; i < n8; i += stride) {
        const float4v* p = (const float4v*)x + (size_t)i * 2;
        float4v a = p[0], b = p[1];
        ushort8 r;
        r[0] = f2bf(a[0]); r[1] = f2bf(a[1]); r[2] = f2bf(a[2]); r[3] = f2bf(a[3]);
        r[4] = f2bf(b[0]); r[5] = f2bf(b[1]); r[6] = f2bf(b[2]); r[7] = f2bf(b[3]);
        *((ushort8*)o + i) = r;
    }
}

// ---------------- prepass 2: W = ternary * group_scale -> bf16 ----------------
__global__ void dequant_w(const int* __restrict__ t, const float* __restrict__ s,
                          unsigned short* __restrict__ o, int n8) {
    int i = blockIdx.x * blockDim.x + threadIdx.x;
    int stride = gridDim.x * blockDim.x;
    for (; i < n8; i += stride) {
        float sc = s[i >> 4];
        const int4v* p = (const int4v*)t + (size_t)i * 2;
        int4v a = p[0], b = p[1];
        ushort8 r;
        r[0] = f2bf((float)a[0] * sc); r[1] = f2bf((float)a[1] * sc);
        r[2] = f2bf((float)a[2] * sc); r[3] = f2bf((float)a[3] * sc);
        r[4] = f2bf((float)b[0] * sc); r[5] = f2bf((float)b[1] * sc);
        r[6] = f2bf((float)b[2] * sc); r[7] = f2bf((float)b[7-7+7] * sc);
        // (note: b[7] does not exist in int4v; correct element below)
        r[7] = f2bf((float)b[3] * sc);
        *((ushort8*)o + i) = r;
    }
}

// ---------------- main GEMM: 256x256 8-phase template ----------------
// 8 waves (2M x 4N), per-wave 128x64 out = 8x4 frags; BK=64 (2 k-steps of 32).
// LDS: 2 buf x {A,B} x 32KB, subtile-blocked [R/16][K/32][16][32] bf16,
// XOR-swizzle: byte ^= ((byte>>9)&1)<<5 within each 1024B subtile.
// Staging: (matrix-pair, k-half) granularity: phases 1/3/5/7 stage 16KB each
// (4 x global_load_lds x16B per thread); waits: vmcnt(4) at phases 4 and 8.
// Issue->wait distance >= 3 phases (was 2 in R2).

#define DSREADS_AB(b, qm, ks) {                                                  \
    _Pragma("unroll") for (int n = 0; n < 4; ++n)                                \
      bfr[n] = *(const short8*)(L + (b)*65536 + 32768 + ((((wc)*4+n)*2+(ks))<<10) + laneA); \
    _Pragma("unroll") for (int m = 0; m < 4; ++m)                                \
      af[m] = *(const short8*)(L + (b)*65536 + ((((wr)*8+(qm)*4+m)*2+(ks))<<10) + laneA); }

#define DSREADS_A(b, qm, ks) {                                                   \
    _Pragma("unroll") for (int m = 0; m < 4; ++m)                                \
      af[m] = *(const short8*)(L + (b)*65536 + ((((wr)*8+(qm)*4+m)*2+(ks))<<10) + laneA); }

#define MFMAS(qm) {                                                              \
    _Pragma("unroll") for (int m = 0; m < 4; ++m)                                \
    _Pragma("unroll") for (int n = 0; n < 4; ++n)                                \
      acc[(qm)*4+m][n] = __builtin_amdgcn_mfma_f32_16x16x32_bf16(af[m], bfr[n], acc[(qm)*4+m][n], 0, 0, 0); }

// MOFF: A=0, B=32768. BOFF: buf0=0, buf1=65536. T: K-tile idx, KH: k-half 0/1.
#define STAGE(PMAT, MOFF, BOFF, T, KH) {                                         \
    _Pragma("unroll") for (int j = 0; j < 2; ++j)                                \
      __builtin_amdgcn_global_load_lds(                                          \
        (const __attribute__((address_space(1))) void*)(PMAT[j] + (T)*64 + (KH)*32), \
        (__attribute__((address_space(3))) void*)(L + (BOFF) + (MOFF) + dOff[j] + (KH)*1024), \
        16, 0, 0); }

#define STAGE_AB(BOFF, T, KH) { STAGE(pA, 0, BOFF, T, KH); STAGE(pB, 32768, BOFF, T, KH); }

#define WAITV4 asm volatile("s_waitcnt vmcnt(4)" ::: "memory");

#define PHASE(READS, QM, STG, WV)                                                \
    READS;                                                                       \
    STG;                                                                         \
    __builtin_amdgcn_sched_barrier(0);                                           \
    __builtin_amdgcn_s_barrier();                                                \
    asm volatile("s_waitcnt lgkmcnt(0)" ::: "memory");                           \
    __builtin_amdgcn_sched_barrier(0);                                           \
    __builtin_amdgcn_s_setprio(1);                                               \
    MFMAS(QM);                                                                   \
    __builtin_amdgcn_s_setprio(0);                                               \
    WV;                                                                          \
    __builtin_amdgcn_sched_barrier(0);                                           \
    __builtin_amdgcn_s_barrier();                                                \
    __builtin_amdgcn_sched_barrier(0);

__global__ __launch_bounds__(512, 2) void gemm_8p(const unsigned short* __restrict__ A,
                                                  const unsigned short* __restrict__ B,
                                                  float* __restrict__ C) {
    __shared__ __align__(16) unsigned char L[131072]; // 128 KiB

    const int tid  = threadIdx.x;
    const int lane = tid & 63;
    const int wid  = tid >> 6;
    const int wr   = wid >> 2;   // 0..1
    const int wc   = wid & 3;    // 0..3

    // T1: bijective chunked XCD swizzle (nwg=512, 512%8==0). y-fastest decode:
    // each XCD's ~32 concurrent blocks share one B-panel (2MB, L2-resident).
    const int wgid = blockIdx.x;
    const int swz  = (wgid & 7) * 64 + (wgid >> 3);
    const int rowBase = (swz & 31) * 256;   // M-tile (32 of them)
    const int colBase = (swz >> 5) * 256;   // N-tile (16 of them)

    // reader per-lane byte offset within a subtile (+swizzle):
    //   r=lane&15, c=lane>>4 : (r*64 + c*16) ^ ((r&8)<<2)
    const int laneA = (((lane & 15) * 64) + ((lane >> 4) * 16)) ^ (((lane >> 3) & 1) << 5);

    // stager: chunk w=lane -> logical (r,kloc); linear dest + inverse-swizzled
    // global source form the same involution as the read swizzle (rule 21):
    //   r = w>>2 ; kloc = (w&1)*8 + (((w>>1)^(w>>5))&1)*16
    const int kloc = (lane & 1) * 8 + (((lane >> 1) ^ (lane >> 5)) & 1) * 16;
    const int r_st = lane >> 2;
    const unsigned short* pA[2];
    const unsigned short* pB[2];
    int dOff[2];
#pragma unroll
    for (int j = 0; j < 2; ++j) {
        int R = (j * 8 + wid) * 16 + r_st;
        pA[j] = A + (size_t)(rowBase + R) * Ksz + kloc;
        pB[j] = B + (size_t)(colBase + R) * Ksz + kloc;
        dOff[j] = (j * 8 + wid) * 2048;
    }

    f32x4 acc[8][4] = {};
    short8 af[4], bfr[4];

    // ---- prologue: T0 (both k-halves) -> buf0, T1 kh0 -> buf1 : 12 loads/wave ----
    STAGE_AB(0,     0, 0);
    STAGE_AB(0,     0, 1);
    STAGE_AB(65536, 1, 0);
    WAITV4                          // T0's 8 loads retired; T1-kh0 (4) may fly
    __builtin_amdgcn_sched_barrier(0);
    __builtin_amdgcn_s_barrier();
    __builtin_amdgcn_sched_barrier(0);

    for (int i = 0; i < 32; ++i) {
        const int t1 = 2 * i + 1;
        const int t2 = (i < 31) ? 2 * i + 2 : 62;  // clamp: last-iter stages are dead writes
        const int t3 = (i < 31) ? 2 * i + 3 : 62;  // into regions no longer read (addrs valid)

        // tile T0=2i in buf0 (phases 1-4), T1=2i+1 in buf1 (phases 5-8).
        // Stage slots at odd phases only (4 loads each); vmcnt(4) at phases 4/8:
        //   P4 needs T1 done: T1kh0 issued prev-P7 (dist 5), T1kh1 issued P1 (dist 3)
        //   P8 needs T2 done: T2kh0 issued P3 (dist 5), T2kh1 issued P5 (dist 3)
        PHASE(DSREADS_AB(0, 0, 0), 0, STAGE_AB(65536, t1, 1), )
        PHASE(DSREADS_A (0, 1, 0), 1,                       , )
        PHASE(DSREADS_AB(0, 1, 1), 1, STAGE_AB(0,     t2, 0), )
        PHASE(DSREADS_A (0, 0, 1), 0,                       , WAITV4)
        PHASE(DSREADS_AB(1, 0, 0), 0, STAGE_AB(0,     t2, 1), )
        PHASE(DSREADS_A (1, 1, 0), 1,                       , )
        PHASE(DSREADS_AB(1, 1, 1), 1, STAGE_AB(65536, t3, 0), )
        PHASE(DSREADS_A (1, 0, 1), 0,                       , WAITV4)
    }

    // drain outstanding gload_lds before LDS teardown / endpgm
    asm volatile("s_waitcnt vmcnt(0)" ::: "memory");

    // epilogue: C/D layout (16x16x32): col = lane&15, row = (lane>>4)*4 + j
    const int crow0 = rowBase + wr * 128 + (lane >> 4) * 4;
    const int ccol0 = colBase + wc * 64 + (lane & 15);
#pragma unroll
    for (int fm = 0; fm < 8; ++fm)
#pragma unroll
        for (int fn = 0; fn < 4; ++fn) {
            float* cp = C + (size_t)(crow0 + fm * 16) * Nsz + ccol0 + fn * 16;
#pragma unroll
            for (int j = 0; j < 4; ++j)
                cp[(size_t)j * Nsz] = acc[fm][fn][j];
        }
}

// ---------------- fallback (ws too small): exact fp32, slow but correct ----------------
__global__ void gemm_naive(const float* __restrict__ x, const int* __restrict__ t,
                           const float* __restrict__ s, float* __restrict__ C) {
    size_t o = (size_t)blockIdx.x * blockDim.x + threadIdx.x;
    if (o >= (size_t)Msz * Nsz) return;
    int m = (int)(o / Nsz), n = (int)(o % Nsz);
    float acc = 0.f;
    for (int g = 0; g < Ksz / 128; ++g) {
        float sc = s[n * (Ksz / 128) + g];
        float p = 0.f;
        const float* xp = x + (size_t)m * Ksz + g * 128;
        const int* tp = t + (size_t)n * Ksz + g * 128;
        for (int k = 0; k < 128; ++k) p += xp[k] * (float)tp[k];
        acc += sc * p;
    }
    C[o] = acc;
}

extern "C" void kernel_launch(void* const* d_in, const int* in_sizes, int n_in,
                              void* d_out, int out_size, void* d_ws, size_t ws_size,
                              hipStream_t stream) {
    const float* x      = (const float*)d_in[0];
    const int*   tern   = (const int*)d_in[1];
    const float* scales = (const float*)d_in[2];
    float* out = (float*)d_out;

    const size_t aBytes = (size_t)Msz * Ksz * 2; // 64 MiB
    const size_t bBytes = (size_t)Nsz * Ksz * 2; // 32 MiB

    if (ws_size >= aBytes + bBytes) {
        unsigned short* Abf = (unsigned short*)d_ws;
        unsigned short* Bbf = (unsigned short*)((char*)d_ws + aBytes);
        cvt_x<<<2048, 256, 0, stream>>>(x, Abf, (int)((size_t)Msz * Ksz / 8));
        dequant_w<<<2048, 256, 0, stream>>>(tern, scales, Bbf, (int)((size_t)Nsz * Ksz / 8));
        gemm_8p<<<dim3((Msz / 256) * (Nsz / 256)), 512, 0, stream>>>(Abf, Bbf, out);
    } else {
        gemm_naive<<<(int)(((size_t)Msz * Nsz + 255) / 256), 256, 0, stream>>>(x, tern, scales, out);
    }
}

// Round 4
// 284.669 us; speedup vs baseline: 1.0700x; 1.0700x over previous
//
#include <hip/hip_runtime.h>
#include <hip/hip_bf16.h>

// C[m][o] = sum_i x[m][i] * ternary[o][i] * scales[o*32 + i/128]
// M=8192, N=4096, K=4096. Fused prepass to bf16 (x cvt + W dequant) in d_ws,
// then 256x256 8-phase bf16 NT-GEMM (T2 swizzle + T3/T4 counted vmcnt + T5 setprio).
// R4: reverted XCD swizzle (R3: FETCH 295->625MB, regression), kept deepened
// odd-phase staging (issue->wait >= 3 phases).

#define Msz 8192
#define Nsz 4096
#define Ksz 4096

typedef __attribute__((ext_vector_type(8))) short short8;
typedef __attribute__((ext_vector_type(4))) float f32x4;
typedef __attribute__((ext_vector_type(4))) int int4v;
typedef __attribute__((ext_vector_type(4))) float float4v;
typedef __attribute__((ext_vector_type(8))) unsigned short ushort8;

static __device__ __forceinline__ unsigned short f2bf(float f) {
    unsigned u = __builtin_bit_cast(unsigned, f);
    u += 0x7fffu + ((u >> 16) & 1u);
    return (unsigned short)(u >> 16);
}

// ---------------- fused prepass: blocks [0,2048) cvt x ; [2048,3072) dequant W ----------------
__global__ void prep(const float* __restrict__ x, const int* __restrict__ t,
                     const float* __restrict__ s,
                     unsigned short* __restrict__ ox, unsigned short* __restrict__ ow) {
    if (blockIdx.x < 2048) {
        int i = blockIdx.x * 256 + threadIdx.x;
        for (; i < Msz * Ksz / 8; i += 2048 * 256) {
            const float4v* p = (const float4v*)x + (size_t)i * 2;
            float4v a = p[0], b = p[1];
            ushort8 r;
            r[0] = f2bf(a[0]); r[1] = f2bf(a[1]); r[2] = f2bf(a[2]); r[3] = f2bf(a[3]);
            r[4] = f2bf(b[0]); r[5] = f2bf(b[1]); r[6] = f2bf(b[2]); r[7] = f2bf(b[3]);
            *((ushort8*)ox + i) = r;
        }
    } else {
        int i = (blockIdx.x - 2048) * 256 + threadIdx.x;
        for (; i < Nsz * Ksz / 8; i += 1024 * 256) {
            float sc = s[i >> 4];  // 8-elem chunk stays inside one 128-group
            const int4v* p = (const int4v*)t + (size_t)i * 2;
            int4v a = p[0], b = p[1];
            ushort8 r;
            r[0] = f2bf((float)a[0] * sc); r[1] = f2bf((float)a[1] * sc);
            r[2] = f2bf((float)a[2] * sc); r[3] = f2bf((float)a[3] * sc);
            r[4] = f2bf((float)b[0] * sc); r[5] = f2bf((float)b[1] * sc);
            r[6] = f2bf((float)b[2] * sc); r[7] = f2bf((float)b[3] * sc);
            *((ushort8*)ow + i) = r;
        }
    }
}

// ---------------- main GEMM: 256x256 8-phase template ----------------
// 8 waves (2M x 4N), per-wave 128x64 out = 8x4 frags; BK=64 (2 k-steps of 32).
// LDS: 2 buf x {A,B} x 32KB, subtile-blocked [R/16][K/32][16][32] bf16,
// XOR-swizzle: byte ^= ((byte>>9)&1)<<5 within each 1024B subtile.
// Staging at odd phases only (16KB = 4 x global_load_lds x16B per thread);
// waits: vmcnt(4) at phases 4 and 8; issue->wait distance 3-5 phases.

#define DSREADS_AB(b, qm, ks) {                                                  \
    _Pragma("unroll") for (int n = 0; n < 4; ++n)                                \
      bfr[n] = *(const short8*)(L + (b)*65536 + 32768 + ((((wc)*4+n)*2+(ks))<<10) + laneA); \
    _Pragma("unroll") for (int m = 0; m < 4; ++m)                                \
      af[m] = *(const short8*)(L + (b)*65536 + ((((wr)*8+(qm)*4+m)*2+(ks))<<10) + laneA); }

#define DSREADS_A(b, qm, ks) {                                                   \
    _Pragma("unroll") for (int m = 0; m < 4; ++m)                                \
      af[m] = *(const short8*)(L + (b)*65536 + ((((wr)*8+(qm)*4+m)*2+(ks))<<10) + laneA); }

#define MFMAS(qm) {                                                              \
    _Pragma("unroll") for (int m = 0; m < 4; ++m)                                \
    _Pragma("unroll") for (int n = 0; n < 4; ++n)                                \
      acc[(qm)*4+m][n] = __builtin_amdgcn_mfma_f32_16x16x32_bf16(af[m], bfr[n], acc[(qm)*4+m][n], 0, 0, 0); }

// MOFF: A=0, B=32768. BOFF: buf0=0, buf1=65536. T: K-tile idx, KH: k-half 0/1.
#define STAGE(PMAT, MOFF, BOFF, T, KH) {                                         \
    _Pragma("unroll") for (int j = 0; j < 2; ++j)                                \
      __builtin_amdgcn_global_load_lds(                                          \
        (const __attribute__((address_space(1))) void*)(PMAT[j] + (T)*64 + (KH)*32), \
        (__attribute__((address_space(3))) void*)(L + (BOFF) + (MOFF) + dOff[j] + (KH)*1024), \
        16, 0, 0); }

#define STAGE_AB(BOFF, T, KH) { STAGE(pA, 0, BOFF, T, KH); STAGE(pB, 32768, BOFF, T, KH); }

#define WAITV4 asm volatile("s_waitcnt vmcnt(4)" ::: "memory");

#define PHASE(READS, QM, STG, WV)                                                \
    READS;                                                                       \
    STG;                                                                         \
    __builtin_amdgcn_sched_barrier(0);                                           \
    __builtin_amdgcn_s_barrier();                                                \
    asm volatile("s_waitcnt lgkmcnt(0)" ::: "memory");                           \
    __builtin_amdgcn_sched_barrier(0);                                           \
    __builtin_amdgcn_s_setprio(1);                                               \
    MFMAS(QM);                                                                   \
    __builtin_amdgcn_s_setprio(0);                                               \
    WV;                                                                          \
    __builtin_amdgcn_sched_barrier(0);                                           \
    __builtin_amdgcn_s_barrier();                                                \
    __builtin_amdgcn_sched_barrier(0);

__global__ __launch_bounds__(512, 2) void gemm_8p(const unsigned short* __restrict__ A,
                                                  const unsigned short* __restrict__ B,
                                                  float* __restrict__ C) {
    __shared__ __align__(16) unsigned char L[131072]; // 128 KiB

    const int tid  = threadIdx.x;
    const int lane = tid & 63;
    const int wid  = tid >> 6;
    const int wr   = wid >> 2;   // 0..1
    const int wc   = wid & 3;    // 0..3
    const int rowBase = blockIdx.y * 256;
    const int colBase = blockIdx.x * 256;

    // reader per-lane byte offset within a subtile (+swizzle):
    //   r=lane&15, c=lane>>4 : (r*64 + c*16) ^ ((r&8)<<2)
    const int laneA = (((lane & 15) * 64) + ((lane >> 4) * 16)) ^ (((lane >> 3) & 1) << 5);

    // stager: chunk w=lane -> logical (r,kloc); linear dest + inverse-swizzled
    // global source form the same involution as the read swizzle (rule 21):
    //   r = w>>2 ; kloc = (w&1)*8 + (((w>>1)^(w>>5))&1)*16
    const int kloc = (lane & 1) * 8 + (((lane >> 1) ^ (lane >> 5)) & 1) * 16;
    const int r_st = lane >> 2;
    const unsigned short* pA[2];
    const unsigned short* pB[2];
    int dOff[2];
#pragma unroll
    for (int j = 0; j < 2; ++j) {
        int R = (j * 8 + wid) * 16 + r_st;
        pA[j] = A + (size_t)(rowBase + R) * Ksz + kloc;
        pB[j] = B + (size_t)(colBase + R) * Ksz + kloc;
        dOff[j] = (j * 8 + wid) * 2048;
    }

    f32x4 acc[8][4] = {};
    short8 af[4], bfr[4];

    // ---- prologue: T0 (both k-halves) -> buf0, T1 kh0 -> buf1 : 12 loads/wave ----
    STAGE_AB(0,     0, 0);
    STAGE_AB(0,     0, 1);
    STAGE_AB(65536, 1, 0);
    WAITV4                          // T0's 8 loads retired; T1-kh0 (4) may fly
    __builtin_amdgcn_sched_barrier(0);
    __builtin_amdgcn_s_barrier();
    __builtin_amdgcn_sched_barrier(0);

    for (int i = 0; i < 32; ++i) {
        const int t1 = 2 * i + 1;
        const int t2 = (i < 31) ? 2 * i + 2 : 62;  // clamp: last-iter stages are dead writes
        const int t3 = (i < 31) ? 2 * i + 3 : 62;  // into regions no longer read (addrs valid)

        // tile T0=2i in buf0 (phases 1-4), T1=2i+1 in buf1 (phases 5-8).
        // Stage slots at odd phases only (4 loads each); vmcnt(4) at phases 4/8:
        //   P4 needs T1 done: T1kh0 issued prev-P7 (dist 5), T1kh1 issued P1 (dist 3)
        //   P8 needs T2 done: T2kh0 issued P3 (dist 5), T2kh1 issued P5 (dist 3)
        PHASE(DSREADS_AB(0, 0, 0), 0, STAGE_AB(65536, t1, 1), )
        PHASE(DSREADS_A (0, 1, 0), 1,                       , )
        PHASE(DSREADS_AB(0, 1, 1), 1, STAGE_AB(0,     t2, 0), )
        PHASE(DSREADS_A (0, 0, 1), 0,                       , WAITV4)
        PHASE(DSREADS_AB(1, 0, 0), 0, STAGE_AB(0,     t2, 1), )
        PHASE(DSREADS_A (1, 1, 0), 1,                       , )
        PHASE(DSREADS_AB(1, 1, 1), 1, STAGE_AB(65536, t3, 0), )
        PHASE(DSREADS_A (1, 0, 1), 0,                       , WAITV4)
    }

    // drain outstanding gload_lds before LDS teardown / endpgm
    asm volatile("s_waitcnt vmcnt(0)" ::: "memory");

    // epilogue: C/D layout (16x16x32): col = lane&15, row = (lane>>4)*4 + j
    const int crow0 = rowBase + wr * 128 + (lane >> 4) * 4;
    const int ccol0 = colBase + wc * 64 + (lane & 15);
#pragma unroll
    for (int fm = 0; fm < 8; ++fm)
#pragma unroll
        for (int fn = 0; fn < 4; ++fn) {
            float* cp = C + (size_t)(crow0 + fm * 16) * Nsz + ccol0 + fn * 16;
#pragma unroll
            for (int j = 0; j < 4; ++j)
                cp[(size_t)j * Nsz] = acc[fm][fn][j];
        }
}

// ---------------- fallback (ws too small): exact fp32, slow but correct ----------------
__global__ void gemm_naive(const float* __restrict__ x, const int* __restrict__ t,
                           const float* __restrict__ s, float* __restrict__ C) {
    size_t o = (size_t)blockIdx.x * blockDim.x + threadIdx.x;
    if (o >= (size_t)Msz * Nsz) return;
    int m = (int)(o / Nsz), n = (int)(o % Nsz);
    float acc = 0.f;
    for (int g = 0; g < Ksz / 128; ++g) {
        float sc = s[n * (Ksz / 128) + g];
        float p = 0.f;
        const float* xp = x + (size_t)m * Ksz + g * 128;
        const int* tp = t + (size_t)n * Ksz + g * 128;
        for (int k = 0; k < 128; ++k) p += xp[k] * (float)tp[k];
        acc += sc * p;
    }
    C[o] = acc;
}

extern "C" void kernel_launch(void* const* d_in, const int* in_sizes, int n_in,
                              void* d_out, int out_size, void* d_ws, size_t ws_size,
                              hipStream_t stream) {
    const float* x      = (const float*)d_in[0];
    const int*   tern   = (const int*)d_in[1];
    const float* scales = (const float*)d_in[2];
    float* out = (float*)d_out;

    const size_t aBytes = (size_t)Msz * Ksz * 2; // 64 MiB
    const size_t bBytes = (size_t)Nsz * Ksz * 2; // 32 MiB

    if (ws_size >= aBytes + bBytes) {
        unsigned short* Abf = (unsigned short*)d_ws;
        unsigned short* Bbf = (unsigned short*)((char*)d_ws + aBytes);
        prep<<<3072, 256, 0, stream>>>(x, tern, scales, Abf, Bbf);
        dim3 grid(Nsz / 256, Msz / 256);
        gemm_8p<<<grid, 512, 0, stream>>>(Abf, Bbf, out);
    } else {
        gemm_naive<<<(int)(((size_t)Msz * Nsz + 255) / 256), 256, 0, stream>>>(x, tern, scales, out);
    }
}

// Round 5
// 266.829 us; speedup vs baseline: 1.1415x; 1.0669x over previous
//
#include <hip/hip_runtime.h>
#include <hip/hip_bf16.h>

// C[m][o] = sum_i x[m][i] * ternary[o][i] * scales[o*32 + i/128]
// M=8192, N=4096, K=4096. Fused prepass to bf16 (x cvt + W dequant) in d_ws,
// then 256x256 8-phase bf16 NT-GEMM, m201-faithful schedule:
//   - stage unit = M-half x full BK=64 (2 gload_lds), 1 unit per phase (smooth)
//   - quadrant q reads A-half q>>1; B read once/tile (12-read phase), held in regs
//   - second tile's quadrants reversed (half1 first) -> deeper safe prefetch
//   - waits: vmcnt(6) at phases 4 and 8 (3 half-tiles in flight, dist 3-6 phases)

#define Msz 8192
#define Nsz 4096
#define Ksz 4096

typedef __attribute__((ext_vector_type(8))) short short8;
typedef __attribute__((ext_vector_type(4))) float f32x4;
typedef __attribute__((ext_vector_type(4))) int int4v;
typedef __attribute__((ext_vector_type(4))) float float4v;
typedef __attribute__((ext_vector_type(8))) unsigned short ushort8;

static __device__ __forceinline__ unsigned short f2bf(float f) {
    unsigned u = __builtin_bit_cast(unsigned, f);
    u += 0x7fffu + ((u >> 16) & 1u);
    return (unsigned short)(u >> 16);
}

// ---------------- fused prepass: blocks [0,2048) cvt x ; [2048,3072) dequant W ----------------
__global__ void prep(const float* __restrict__ x, const int* __restrict__ t,
                     const float* __restrict__ s,
                     unsigned short* __restrict__ ox, unsigned short* __restrict__ ow) {
    if (blockIdx.x < 2048) {
        int i = blockIdx.x * 256 + threadIdx.x;
        for (; i < Msz * Ksz / 8; i += 2048 * 256) {
            const float4v* p = (const float4v*)x + (size_t)i * 2;
            float4v a = p[0], b = p[1];
            ushort8 r;
            r[0] = f2bf(a[0]); r[1] = f2bf(a[1]); r[2] = f2bf(a[2]); r[3] = f2bf(a[3]);
            r[4] = f2bf(b[0]); r[5] = f2bf(b[1]); r[6] = f2bf(b[2]); r[7] = f2bf(b[3]);
            *((ushort8*)ox + i) = r;
        }
    } else {
        int i = (blockIdx.x - 2048) * 256 + threadIdx.x;
        for (; i < Nsz * Ksz / 8; i += 1024 * 256) {
            float sc = s[i >> 4];  // 8-elem chunk stays inside one 128-group
            const int4v* p = (const int4v*)t + (size_t)i * 2;
            int4v a = p[0], b = p[1];
            ushort8 r;
            r[0] = f2bf((float)a[0] * sc); r[1] = f2bf((float)a[1] * sc);
            r[2] = f2bf((float)a[2] * sc); r[3] = f2bf((float)a[3] * sc);
            r[4] = f2bf((float)b[0] * sc); r[5] = f2bf((float)b[1] * sc);
            r[6] = f2bf((float)b[2] * sc); r[7] = f2bf((float)b[3] * sc);
            *((ushort8*)ow + i) = r;
        }
    }
}

// ---------------- main GEMM ----------------
// 8 waves (2M x 4N). Per-wave 8 M-frags at rowTile = q*4 + wr*2 + m (q=0..3,m=0..1)
// so quadrant q lies in M-half q>>1. Per-wave N: cols wc*64..+63 (4 frags).
// LDS per buf: A 32KB ([rowTile 0..15][ks 0..1] subtiles of 1KB), B 32KB same by colTile.
// Subtile swizzle (verified R2): read byte (r*64+c*16)^((r&8)<<2); stage via
// linear dest + inverse-swizzled source k-offset (kloc).

#define READ_B(b) {                                                              \
    _Pragma("unroll") for (int n = 0; n < 4; ++n)                                \
    _Pragma("unroll") for (int ks = 0; ks < 2; ++ks)                             \
      bfr[n][ks] = *(const short8*)(L + (b)*65536 + 32768 + ((((wc)*4+n)*2+ks)<<10) + laneA); }

#define READ_A(b, q) {                                                           \
    _Pragma("unroll") for (int m = 0; m < 2; ++m)                                \
    _Pragma("unroll") for (int ks = 0; ks < 2; ++ks)                             \
      af[m][ks] = *(const short8*)(L + (b)*65536 + ((((q)*4+(wr)*2+m)*2+ks)<<10) + laneA); }

#define MFMAS(q) {                                                               \
    _Pragma("unroll") for (int m = 0; m < 2; ++m)                                \
    _Pragma("unroll") for (int n = 0; n < 4; ++n) {                              \
      acc[(q)*2+m][n] = __builtin_amdgcn_mfma_f32_16x16x32_bf16(af[m][0], bfr[n][0], acc[(q)*2+m][n], 0, 0, 0); \
      acc[(q)*2+m][n] = __builtin_amdgcn_mfma_f32_16x16x32_bf16(af[m][1], bfr[n][1], acc[(q)*2+m][n], 0, 0, 0); } }

// Stage one M-half (128 rows x K=64 = 16KB) of matrix PM at K-tile T into
// LDS region BOFF+MOFF+H*16384. Wave wid writes subtile st = H*16+j*8+wid
// (rowTile st>>1, ks = wid&1) linearly at st*1024 + lane*16.
#define STAGE_H(PM, MOFF, BOFF, T, H) {                                          \
    _Pragma("unroll") for (int j = 0; j < 2; ++j)                                \
      __builtin_amdgcn_global_load_lds(                                          \
        (const __attribute__((address_space(1))) void*)(PM + (size_t)((H)*128 + j*64)*Ksz + (T)*64), \
        (__attribute__((address_space(3))) void*)(L + (BOFF) + (MOFF) + (H)*16384 + j*8192 + dOff), \
        16, 0, 0); }

#define WAITV6 asm volatile("s_waitcnt vmcnt(6)" ::: "memory");

#define PHASE(READS, QM, STG, WV)                                                \
    READS;                                                                       \
    STG;                                                                         \
    __builtin_amdgcn_sched_barrier(0);                                           \
    __builtin_amdgcn_s_barrier();                                                \
    asm volatile("s_waitcnt lgkmcnt(0)" ::: "memory");                           \
    __builtin_amdgcn_sched_barrier(0);                                           \
    __builtin_amdgcn_s_setprio(1);                                               \
    MFMAS(QM);                                                                   \
    __builtin_amdgcn_s_setprio(0);                                               \
    WV;                                                                          \
    __builtin_amdgcn_sched_barrier(0);                                           \
    __builtin_amdgcn_s_barrier();                                                \
    __builtin_amdgcn_sched_barrier(0);

__global__ __launch_bounds__(512, 2) void gemm_8p(const unsigned short* __restrict__ A,
                                                  const unsigned short* __restrict__ B,
                                                  float* __restrict__ C) {
    __shared__ __align__(16) unsigned char L[131072]; // 128 KiB

    const int tid  = threadIdx.x;
    const int lane = tid & 63;
    const int wid  = tid >> 6;
    const int wr   = wid >> 2;   // 0..1
    const int wc   = wid & 3;    // 0..3
    const int rowBase = blockIdx.y * 256;
    const int colBase = blockIdx.x * 256;

    // reader swizzled per-lane byte offset within a 1KB subtile
    const int laneA = (((lane & 15) * 64) + ((lane >> 4) * 16)) ^ (((lane >> 3) & 1) << 5);
    // stager inverse-swizzled per-lane source k-offset (verified involution)
    const int kloc = (lane & 1) * 8 + (((lane >> 1) ^ (lane >> 5)) & 1) * 16;
    const int r_st = lane >> 2;
    const int dOff = wid * 1024;

    const unsigned short* pAb = A + (size_t)(rowBase + (wid >> 1) * 16 + r_st) * Ksz + (wid & 1) * 32 + kloc;
    const unsigned short* pBb = B + (size_t)(colBase + (wid >> 1) * 16 + r_st) * Ksz + (wid & 1) * 32 + kloc;

    f32x4 acc[8][4] = {};
    short8 af[2][2], bfr[4][2];

    // ---- prologue: t0 fully (4 units) + t1.{Bh0,Ah1,Bh1} (3 units) = 14 loads ----
    STAGE_H(pBb, 32768, 0,     0, 0);
    STAGE_H(pAb, 0,     0,     0, 0);
    STAGE_H(pBb, 32768, 0,     0, 1);
    STAGE_H(pAb, 0,     0,     0, 1);
    STAGE_H(pBb, 32768, 65536, 1, 0);
    STAGE_H(pAb, 0,     65536, 1, 1);
    STAGE_H(pBb, 32768, 65536, 1, 1);
    WAITV6                       // retires t0's 8 loads; t1's 6 stay in flight
    __builtin_amdgcn_sched_barrier(0);
    __builtin_amdgcn_s_barrier();
    __builtin_amdgcn_sched_barrier(0);

    for (int i = 0; i < 32; ++i) {
        const int t1 = 2 * i + 1;
        const int t2 = (i < 31) ? 2 * i + 2 : 62;  // clamp: last-iter stages are
        const int t3 = (i < 31) ? 2 * i + 3 : 62;  // dead writes into freed regions

        // tile t=2i in buf0: quadrants 0,1 (A-half0) then 2,3 (A-half1)
        PHASE({ READ_B(0); READ_A(0, 0); }, 0, STAGE_H(pAb, 0,     65536, t1, 0), )
        PHASE(READ_A(0, 1),                 1, STAGE_H(pBb, 32768, 0,     t2, 0), )
        PHASE(READ_A(0, 2),                 2, STAGE_H(pAb, 0,     0,     t2, 0), )
        PHASE(READ_A(0, 3),                 3, STAGE_H(pBb, 32768, 0,     t2, 1), WAITV6)
        // tile t+1 in buf1: reversed quadrant order 2,3 (half1) then 0,1 (half0)
        PHASE({ READ_B(1); READ_A(1, 2); }, 2, STAGE_H(pAb, 0,     0,     t2, 1), )
        PHASE(READ_A(1, 3),                 3, STAGE_H(pBb, 32768, 65536, t3, 0), )
        PHASE(READ_A(1, 0),                 0, STAGE_H(pAb, 0,     65536, t3, 1), )
        PHASE(READ_A(1, 1),                 1, STAGE_H(pBb, 32768, 65536, t3, 1), WAITV6)
    }

    // drain outstanding gload_lds before LDS teardown / endpgm
    asm volatile("s_waitcnt vmcnt(0)" ::: "memory");

    // epilogue: frag (q,m) at rowTile q*4+wr*2+m; C/D: col=lane&15, row=(lane>>4)*4+j
    const int crl = (lane >> 4) * 4;
    const int ccol0 = colBase + wc * 64 + (lane & 15);
#pragma unroll
    for (int q = 0; q < 4; ++q)
#pragma unroll
        for (int m = 0; m < 2; ++m)
#pragma unroll
            for (int n = 0; n < 4; ++n) {
                const int row0 = rowBase + (q * 4 + wr * 2 + m) * 16 + crl;
                float* cp = C + (size_t)row0 * Nsz + ccol0 + n * 16;
#pragma unroll
                for (int j = 0; j < 4; ++j)
                    cp[(size_t)j * Nsz] = acc[q * 2 + m][n][j];
            }
}

// ---------------- fallback (ws too small): exact fp32, slow but correct ----------------
__global__ void gemm_naive(const float* __restrict__ x, const int* __restrict__ t,
                           const float* __restrict__ s, float* __restrict__ C) {
    size_t o = (size_t)blockIdx.x * blockDim.x + threadIdx.x;
    if (o >= (size_t)Msz * Nsz) return;
    int m = (int)(o / Nsz), n = (int)(o % Nsz);
    float acc = 0.f;
    for (int g = 0; g < Ksz / 128; ++g) {
        float sc = s[n * (Ksz / 128) + g];
        float p = 0.f;
        const float* xp = x + (size_t)m * Ksz + g * 128;
        const int* tp = t + (size_t)n * Ksz + g * 128;
        for (int k = 0; k < 128; ++k) p += xp[k] * (float)tp[k];
        acc += sc * p;
    }
    C[o] = acc;
}

extern "C" void kernel_launch(void* const* d_in, const int* in_sizes, int n_in,
                              void* d_out, int out_size, void* d_ws, size_t ws_size,
                              hipStream_t stream) {
    const float* x      = (const float*)d_in[0];
    const int*   tern   = (const int*)d_in[1];
    const float* scales = (const float*)d_in[2];
    float* out = (float*)d_out;

    const size_t aBytes = (size_t)Msz * Ksz * 2; // 64 MiB
    const size_t bBytes = (size_t)Nsz * Ksz * 2; // 32 MiB

    if (ws_size >= aBytes + bBytes) {
        unsigned short* Abf = (unsigned short*)d_ws;
        unsigned short* Bbf = (unsigned short*)((char*)d_ws + aBytes);
        prep<<<3072, 256, 0, stream>>>(x, tern, scales, Abf, Bbf);
        dim3 grid(Nsz / 256, Msz / 256);
        gemm_8p<<<grid, 512, 0, stream>>>(Abf, Bbf, out);
    } else {
        gemm_naive<<<(int)(((size_t)Msz * Nsz + 255) / 256), 256, 0, stream>>>(x, tern, scales, out);
    }
}

// Round 6
// 266.041 us; speedup vs baseline: 1.1449x; 1.0030x over previous
//
#include <hip/hip_runtime.h>
#include <hip/hip_bf16.h>

// C[m][o] = sum_i x[m][i] * ternary[o][i] * scales[o*32 + i/128]
// M=8192, N=4096, K=4096. Fused prepass to bf16 (x cvt + W dequant) in d_ws,
// then 256x256 8-phase bf16 NT-GEMM.
// R6: exact split waits — 1 stage unit (2 gload_lds) per phase, waits
// vmcnt(10)/(8)/(10)/(8) at P2/P4/P6/P8 retiring exactly what the next
// phase's reads need; >=4-phase cover per load (R5: min 3, over-retiring).

#define Msz 8192
#define Nsz 4096
#define Ksz 4096

typedef __attribute__((ext_vector_type(8))) short short8;
typedef __attribute__((ext_vector_type(4))) float f32x4;
typedef __attribute__((ext_vector_type(4))) int int4v;
typedef __attribute__((ext_vector_type(4))) float float4v;
typedef __attribute__((ext_vector_type(8))) unsigned short ushort8;

static __device__ __forceinline__ unsigned short f2bf(float f) {
    unsigned u = __builtin_bit_cast(unsigned, f);
    u += 0x7fffu + ((u >> 16) & 1u);
    return (unsigned short)(u >> 16);
}

// ---------------- fused prepass: blocks [0,2048) cvt x ; [2048,3072) dequant W ----------------
__global__ void prep(const float* __restrict__ x, const int* __restrict__ t,
                     const float* __restrict__ s,
                     unsigned short* __restrict__ ox, unsigned short* __restrict__ ow) {
    if (blockIdx.x < 2048) {
        int i = blockIdx.x * 256 + threadIdx.x;
        for (; i < Msz * Ksz / 8; i += 2048 * 256) {
            const float4v* p = (const float4v*)x + (size_t)i * 2;
            float4v a = p[0], b = p[1];
            ushort8 r;
            r[0] = f2bf(a[0]); r[1] = f2bf(a[1]); r[2] = f2bf(a[2]); r[3] = f2bf(a[3]);
            r[4] = f2bf(b[0]); r[5] = f2bf(b[1]); r[6] = f2bf(b[2]); r[7] = f2bf(b[3]);
            *((ushort8*)ox + i) = r;
        }
    } else {
        int i = (blockIdx.x - 2048) * 256 + threadIdx.x;
        for (; i < Nsz * Ksz / 8; i += 1024 * 256) {
            float sc = s[i >> 4];  // 8-elem chunk stays inside one 128-group
            const int4v* p = (const int4v*)t + (size_t)i * 2;
            int4v a = p[0], b = p[1];
            ushort8 r;
            r[0] = f2bf((float)a[0] * sc); r[1] = f2bf((float)a[1] * sc);
            r[2] = f2bf((float)a[2] * sc); r[3] = f2bf((float)a[3] * sc);
            r[4] = f2bf((float)b[0] * sc); r[5] = f2bf((float)b[1] * sc);
            r[6] = f2bf((float)b[2] * sc); r[7] = f2bf((float)b[3] * sc);
            *((ushort8*)ow + i) = r;
        }
    }
}

// ---------------- main GEMM ----------------
// 8 waves (2M x 4N). Per-wave 8 M-frags at rowTile = q*4 + wr*2 + m (q=0..3,m=0..1)
// so quadrant q lies in M-half q>>1. Per-wave N: cols wc*64..+63 (4 frags).
// Tile t=2i in buf0 (phases 1-4, quadrants 0,1,2,3); t'=2i+1 in buf1
// (phases 5-8, quadrants 2,3,0,1 — reversed so A.h0 is read last).
// Stage slots (1 unit = M-half x BK=64 = 2 gload_lds, per phase):
//   P1: t'.A.h0->buf1   P2: t''.B.h0->buf0  P3: t''.A.h0  P4: t''.B.h1
//   P5: t''.A.h1        P6: t'''.B.h0->buf1 P7: t'''.A.h1 P8: t'''.B.h1
// Exact waits (retire exactly next phase's dependencies):
//   P2: vmcnt(10) [t.A.h1]   P4: vmcnt(8) [t'.B,A.h1]
//   P6: vmcnt(10) [t'.A.h0]  P8: vmcnt(8) [t''.B.h0,A.h0,B.h1]

#define READ_B(b) {                                                              \
    _Pragma("unroll") for (int n = 0; n < 4; ++n)                                \
    _Pragma("unroll") for (int ks = 0; ks < 2; ++ks)                             \
      bfr[n][ks] = *(const short8*)(L + (b)*65536 + 32768 + ((((wc)*4+n)*2+ks)<<10) + laneA); }

#define READ_A(b, q) {                                                           \
    _Pragma("unroll") for (int m = 0; m < 2; ++m)                                \
    _Pragma("unroll") for (int ks = 0; ks < 2; ++ks)                             \
      af[m][ks] = *(const short8*)(L + (b)*65536 + ((((q)*4+(wr)*2+m)*2+ks)<<10) + laneA); }

#define MFMAS(q) {                                                               \
    _Pragma("unroll") for (int m = 0; m < 2; ++m)                                \
    _Pragma("unroll") for (int n = 0; n < 4; ++n) {                              \
      acc[(q)*2+m][n] = __builtin_amdgcn_mfma_f32_16x16x32_bf16(af[m][0], bfr[n][0], acc[(q)*2+m][n], 0, 0, 0); \
      acc[(q)*2+m][n] = __builtin_amdgcn_mfma_f32_16x16x32_bf16(af[m][1], bfr[n][1], acc[(q)*2+m][n], 0, 0, 0); } }

// Stage one M-half (128 rows x K=64 = 16KB) of matrix PM at K-tile T into
// LDS region BOFF+MOFF+H*16384. Wave wid writes subtiles H*16+{wid, 8+wid}.
#define STAGE_H(PM, MOFF, BOFF, T, H) {                                          \
    _Pragma("unroll") for (int j = 0; j < 2; ++j)                                \
      __builtin_amdgcn_global_load_lds(                                          \
        (const __attribute__((address_space(1))) void*)(PM + (size_t)((H)*128 + j*64)*Ksz + (T)*64), \
        (__attribute__((address_space(3))) void*)(L + (BOFF) + (MOFF) + (H)*16384 + j*8192 + dOff), \
        16, 0, 0); }

#define WAITV8  asm volatile("s_waitcnt vmcnt(8)"  ::: "memory");
#define WAITV10 asm volatile("s_waitcnt vmcnt(10)" ::: "memory");

#define PHASE(READS, QM, STG, WV)                                                \
    READS;                                                                       \
    STG;                                                                         \
    __builtin_amdgcn_sched_barrier(0);                                           \
    __builtin_amdgcn_s_barrier();                                                \
    asm volatile("s_waitcnt lgkmcnt(0)" ::: "memory");                           \
    __builtin_amdgcn_sched_barrier(0);                                           \
    __builtin_amdgcn_s_setprio(1);                                               \
    MFMAS(QM);                                                                   \
    __builtin_amdgcn_s_setprio(0);                                               \
    WV;                                                                          \
    __builtin_amdgcn_sched_barrier(0);                                           \
    __builtin_amdgcn_s_barrier();                                                \
    __builtin_amdgcn_sched_barrier(0);

__global__ __launch_bounds__(512, 2) void gemm_8p(const unsigned short* __restrict__ A,
                                                  const unsigned short* __restrict__ B,
                                                  float* __restrict__ C) {
    __shared__ __align__(16) unsigned char L[131072]; // 128 KiB

    const int tid  = threadIdx.x;
    const int lane = tid & 63;
    const int wid  = tid >> 6;
    const int wr   = wid >> 2;   // 0..1
    const int wc   = wid & 3;    // 0..3
    const int rowBase = blockIdx.y * 256;
    const int colBase = blockIdx.x * 256;

    // reader swizzled per-lane byte offset within a 1KB subtile
    const int laneA = (((lane & 15) * 64) + ((lane >> 4) * 16)) ^ (((lane >> 3) & 1) << 5);
    // stager inverse-swizzled per-lane source k-offset (verified involution)
    const int kloc = (lane & 1) * 8 + (((lane >> 1) ^ (lane >> 5)) & 1) * 16;
    const int r_st = lane >> 2;
    const int dOff = wid * 1024;

    const unsigned short* pAb = A + (size_t)(rowBase + (wid >> 1) * 16 + r_st) * Ksz + (wid & 1) * 32 + kloc;
    const unsigned short* pBb = B + (size_t)(colBase + (wid >> 1) * 16 + r_st) * Ksz + (wid & 1) * 32 + kloc;

    f32x4 acc[8][4] = {};
    short8 af[2][2], bfr[4][2];

    // ---- prologue: t0.{B.h0,A.h0,B.h1} first (retired by the wait), then
    //      t0.A.h1 + t1.{B.h0,A.h1,B.h1} (stay in flight) = 14 loads ----
    STAGE_H(pBb, 32768, 0,     0, 0);
    STAGE_H(pAb, 0,     0,     0, 0);
    STAGE_H(pBb, 32768, 0,     0, 1);
    STAGE_H(pAb, 0,     0,     0, 1);
    STAGE_H(pBb, 32768, 65536, 1, 0);
    STAGE_H(pAb, 0,     65536, 1, 1);
    STAGE_H(pBb, 32768, 65536, 1, 1);
    WAITV8                       // retires t0.{B.h0,A.h0,B.h1}; 8 stay in flight
    __builtin_amdgcn_sched_barrier(0);
    __builtin_amdgcn_s_barrier();
    __builtin_amdgcn_sched_barrier(0);

    for (int i = 0; i < 32; ++i) {
        const int t1 = 2 * i + 1;
        const int t2 = (i < 31) ? 2 * i + 2 : 62;  // clamp: last-iter stages are
        const int t3 = (i < 31) ? 2 * i + 3 : 62;  // dead writes into freed regions

        PHASE({ READ_B(0); READ_A(0, 0); }, 0, STAGE_H(pAb, 0,     65536, t1, 0), )        // P1
        PHASE(READ_A(0, 1),                 1, STAGE_H(pBb, 32768, 0,     t2, 0), WAITV10) // P2
        PHASE(READ_A(0, 2),                 2, STAGE_H(pAb, 0,     0,     t2, 0), )        // P3
        PHASE(READ_A(0, 3),                 3, STAGE_H(pBb, 32768, 0,     t2, 1), WAITV8)  // P4
        PHASE({ READ_B(1); READ_A(1, 2); }, 2, STAGE_H(pAb, 0,     0,     t2, 1), )        // P5
        PHASE(READ_A(1, 3),                 3, STAGE_H(pBb, 32768, 65536, t3, 0), WAITV10) // P6
        PHASE(READ_A(1, 0),                 0, STAGE_H(pAb, 0,     65536, t3, 1), )        // P7
        PHASE(READ_A(1, 1),                 1, STAGE_H(pBb, 32768, 65536, t3, 1), WAITV8)  // P8
    }

    // drain outstanding gload_lds before LDS teardown / endpgm
    asm volatile("s_waitcnt vmcnt(0)" ::: "memory");

    // epilogue: frag (q,m) at rowTile q*4+wr*2+m; C/D: col=lane&15, row=(lane>>4)*4+j
    const int crl = (lane >> 4) * 4;
    const int ccol0 = colBase + wc * 64 + (lane & 15);
#pragma unroll
    for (int q = 0; q < 4; ++q)
#pragma unroll
        for (int m = 0; m < 2; ++m)
#pragma unroll
            for (int n = 0; n < 4; ++n) {
                const int row0 = rowBase + (q * 4 + wr * 2 + m) * 16 + crl;
                float* cp = C + (size_t)row0 * Nsz + ccol0 + n * 16;
#pragma unroll
                for (int j = 0; j < 4; ++j)
                    cp[(size_t)j * Nsz] = acc[q * 2 + m][n][j];
            }
}

// ---------------- fallback (ws too small): exact fp32, slow but correct ----------------
__global__ void gemm_naive(const float* __restrict__ x, const int* __restrict__ t,
                           const float* __restrict__ s, float* __restrict__ C) {
    size_t o = (size_t)blockIdx.x * blockDim.x + threadIdx.x;
    if (o >= (size_t)Msz * Nsz) return;
    int m = (int)(o / Nsz), n = (int)(o % Nsz);
    float acc = 0.f;
    for (int g = 0; g < Ksz / 128; ++g) {
        float sc = s[n * (Ksz / 128) + g];
        float p = 0.f;
        const float* xp = x + (size_t)m * Ksz + g * 128;
        const int* tp = t + (size_t)n * Ksz + g * 128;
        for (int k = 0; k < 128; ++k) p += xp[k] * (float)tp[k];
        acc += sc * p;
    }
    C[o] = acc;
}

extern "C" void kernel_launch(void* const* d_in, const int* in_sizes, int n_in,
                              void* d_out, int out_size, void* d_ws, size_t ws_size,
                              hipStream_t stream) {
    const float* x      = (const float*)d_in[0];
    const int*   tern   = (const int*)d_in[1];
    const float* scales = (const float*)d_in[2];
    float* out = (float*)d_out;

    const size_t aBytes = (size_t)Msz * Ksz * 2; // 64 MiB
    const size_t bBytes = (size_t)Nsz * Ksz * 2; // 32 MiB

    if (ws_size >= aBytes + bBytes) {
        unsigned short* Abf = (unsigned short*)d_ws;
        unsigned short* Bbf = (unsigned short*)((char*)d_ws + aBytes);
        prep<<<3072, 256, 0, stream>>>(x, tern, scales, Abf, Bbf);
        dim3 grid(Nsz / 256, Msz / 256);
        gemm_8p<<<grid, 512, 0, stream>>>(Abf, Bbf, out);
    } else {
        gemm_naive<<<(int)(((size_t)Msz * Nsz + 255) / 256), 256, 0, stream>>>(x, tern, scales, out);
    }
}